// Round 1
// baseline (197.619 us; speedup 1.0000x reference)
//
#include <hip/hip_runtime.h>
#include <cstddef>

#define NB 32
#define HQ 2048
#define SMAX 4096
#define NKVH 4
#define NHEAD 16
#define HDIM 128
#define QKV_N 3072
#define ATT_SCALE 0.08838834764831845f
#define KSPLIT 8

__device__ __forceinline__ float4 f4max(float4 a, float4 b) {
  return make_float4(fmaxf(a.x, b.x), fmaxf(a.y, b.y), fmaxf(a.z, b.z), fmaxf(a.w, b.w));
}

// ---------------------------------------------------------------------------
// GEMV-ish projection: Y_part[ksb][32][N] = X[32][2048] @ W[2048][N] (K-split)
// grid: (N/64, KSPLIT), block 256 = 64 cols x 4 ksub
// ---------------------------------------------------------------------------
template <int N>
__global__ __launch_bounds__(256) void proj_kernel(const float* __restrict__ X,
                                                   const float* __restrict__ W,
                                                   float* __restrict__ part) {
  __shared__ float x_lds[32][64];
  __shared__ float red[32][4][64];
  const int t = threadIdx.x;
  const int c0 = blockIdx.x << 6;
  const int ksb = blockIdx.y;
  const int k0base = ksb << 8;  // * 256
  const int c = t & 63;
  const int ksub = t >> 6;

  float acc[32];
#pragma unroll
  for (int b = 0; b < 32; ++b) acc[b] = 0.f;

  for (int kt = 0; kt < 256; kt += 64) {
    const int k0 = k0base + kt;
    __syncthreads();  // protect x_lds readers of previous iteration
#pragma unroll
    for (int i = 0; i < 2; ++i) {
      const int idx = t + (i << 8);
      const int bb = idx >> 4, k4 = idx & 15;
      *reinterpret_cast<float4*>(&x_lds[bb][k4 << 2]) =
          *reinterpret_cast<const float4*>(X + bb * HQ + k0 + (k4 << 2));
    }
    __syncthreads();
#pragma unroll
    for (int kk4 = 0; kk4 < 4; ++kk4) {
      const int kk = (ksub << 4) + (kk4 << 2);
      const float* wp = W + (size_t)(k0 + kk) * N + c0 + c;
      const float w0 = wp[0];
      const float w1 = wp[N];
      const float w2 = wp[2 * N];
      const float w3 = wp[3 * N];
#pragma unroll
      for (int b = 0; b < 32; ++b) {
        const float4 x4 = *reinterpret_cast<const float4*>(&x_lds[b][kk]);
        acc[b] = fmaf(x4.x, w0, acc[b]);
        acc[b] = fmaf(x4.y, w1, acc[b]);
        acc[b] = fmaf(x4.z, w2, acc[b]);
        acc[b] = fmaf(x4.w, w3, acc[b]);
      }
    }
  }
  __syncthreads();
#pragma unroll
  for (int b = 0; b < 32; ++b) red[b][ksub][c] = acc[b];
  __syncthreads();
#pragma unroll
  for (int i = 0; i < 8; ++i) {
    const int o = t + (i << 8);
    const int b = o >> 6, cc = o & 63;
    const float v = red[b][0][cc] + red[b][1][cc] + red[b][2][cc] + red[b][3][cc];
    part[(size_t)(ksb * 32 + b) * N + c0 + cc] = v;
  }
}

// ---------------------------------------------------------------------------
// Reduce K-split partials (+ optional bias)
// ---------------------------------------------------------------------------
template <int NCOL, bool HAS_BIAS>
__global__ __launch_bounds__(256) void reduce_kernel(const float* __restrict__ part,
                                                     const float* __restrict__ bias,
                                                     float* __restrict__ out) {
  const int o = blockIdx.x * 256 + threadIdx.x;
  constexpr int total = 32 * NCOL;
  float s = 0.f;
#pragma unroll
  for (int ks = 0; ks < KSPLIT; ++ks) s += part[(size_t)ks * total + o];
  if (HAS_BIAS) s += bias[o % NCOL];
  out[o] = s;
}

// ---------------------------------------------------------------------------
// Flash-decode attention, CHUNK=512. grid = B*NKV*8, block 256.
// qkv: [32][3072] (q | k | v). outputs: ml[1024][8] (m4,l4), accp[1024][4][128]
// ---------------------------------------------------------------------------
__global__ __launch_bounds__(256) void attn_kernel(const float* __restrict__ cache,
                                                   const int* __restrict__ seq_lens,
                                                   const int* __restrict__ slot_map,
                                                   const float* __restrict__ qkv,
                                                   float* __restrict__ ml,
                                                   float* __restrict__ accp) {
  __shared__ float tile[64][132];  // K subtile quarters (wave-private) / V tiles (block)
  __shared__ float qt[4][516];     // 4 padded copies of q^T: [d][4 heads]
  __shared__ float pt[512][4];     // scores -> probs, [s][4 heads]
  __shared__ float redm[4][4];
  __shared__ float redl[4][4];
  __shared__ float obuf[128][4];

  const int t = threadIdx.x;
  const int bid = blockIdx.x;
  const int chunk = bid & 7;
  const int kvh = (bid >> 3) & 3;
  const int b = bid >> 5;
  const int L = seq_lens[b];
  const int start = chunk << 9;
  if (start >= L) return;
  const int n = min(512, L - start);
  const int slot = slot_map[b];
  const float* __restrict__ qrow = qkv + b * QKV_N;
  const float* __restrict__ knew = qrow + 2048 + kvh * HDIM;
  const float* __restrict__ vnew = qrow + 2560 + kvh * HDIM;

  // fill qt: qt[copy][d*4+g] = q[head kvh*4+g][d]
#pragma unroll
  for (int i = 0; i < 8; ++i) {
    const int idx = t + (i << 8);  // 0..2047
    const int cp = idx >> 9;
    const int rem = idx & 511;
    const int d = rem >> 2, g = rem & 3;
    qt[cp][rem] = qrow[((kvh << 2) + g) * HDIM + d];
  }
  __syncthreads();

  const int w = t >> 6, l = t & 63;
  const int sq = l >> 2, dg = l & 3;
  float4 m4 = make_float4(-1e30f, -1e30f, -1e30f, -1e30f);

  // ---- score phase (wave-private, no block barriers) ----
  {
    float* tw = &tile[w << 4][0];
    const float* qtp = &qt[dg][0];
    const int wbase = w << 7;  // wave covers chunk-local s in [wbase, wbase+128)
    const int nst = (n > wbase) ? min(8, (n - wbase + 15) >> 4) : 0;
    for (int st = 0; st < nst; ++st) {
      const int sbase = start + wbase + (st << 4);
      // stage 16 K rows into this wave's quarter of tile
#pragma unroll
      for (int i = 0; i < 8; ++i) {
        const int idx = l + (i << 6);
        const int sl = idx >> 5, d4 = idx & 31;
        const int sg = sbase + sl;
        const float4 v =
            (sg == slot)
                ? *reinterpret_cast<const float4*>(knew + (d4 << 2))
                : *reinterpret_cast<const float4*>(cache + ((size_t)((b << 12) + sg) << 10) +
                                                   (kvh << 7) + (d4 << 2));
        *reinterpret_cast<float4*>(tw + sl * 132 + (d4 << 2)) = v;
      }
      asm volatile("s_waitcnt lgkmcnt(0)" ::: "memory");  // wave-local stage->read fence
      // per-thread partial dot: s = sq, dims [dg*32, dg*32+32)
      const float* trow = tw + sq * 132;
      float4 sc = make_float4(0.f, 0.f, 0.f, 0.f);
#pragma unroll
      for (int i = 0; i < 8; ++i) {
        const int d4i = (dg << 3) + i;
        const float4 k4 = *reinterpret_cast<const float4*>(trow + (d4i << 2));
        const float* qb = qtp + (d4i << 4);
        const float4 q0 = *reinterpret_cast<const float4*>(qb);
        const float4 q1 = *reinterpret_cast<const float4*>(qb + 4);
        const float4 q2 = *reinterpret_cast<const float4*>(qb + 8);
        const float4 q3 = *reinterpret_cast<const float4*>(qb + 12);
        sc.x = fmaf(k4.x, q0.x, sc.x); sc.y = fmaf(k4.x, q0.y, sc.y);
        sc.z = fmaf(k4.x, q0.z, sc.z); sc.w = fmaf(k4.x, q0.w, sc.w);
        sc.x = fmaf(k4.y, q1.x, sc.x); sc.y = fmaf(k4.y, q1.y, sc.y);
        sc.z = fmaf(k4.y, q1.z, sc.z); sc.w = fmaf(k4.y, q1.w, sc.w);
        sc.x = fmaf(k4.z, q2.x, sc.x); sc.y = fmaf(k4.z, q2.y, sc.y);
        sc.z = fmaf(k4.z, q2.z, sc.z); sc.w = fmaf(k4.z, q2.w, sc.w);
        sc.x = fmaf(k4.w, q3.x, sc.x); sc.y = fmaf(k4.w, q3.y, sc.y);
        sc.z = fmaf(k4.w, q3.z, sc.z); sc.w = fmaf(k4.w, q3.w, sc.w);
      }
      // combine 4 dim-groups (adjacent lanes)
      sc.x += __shfl_xor(sc.x, 1); sc.y += __shfl_xor(sc.y, 1);
      sc.z += __shfl_xor(sc.z, 1); sc.w += __shfl_xor(sc.w, 1);
      sc.x += __shfl_xor(sc.x, 2); sc.y += __shfl_xor(sc.y, 2);
      sc.z += __shfl_xor(sc.z, 2); sc.w += __shfl_xor(sc.w, 2);
      float4 scores = make_float4(sc.x * ATT_SCALE, sc.y * ATT_SCALE,
                                  sc.z * ATT_SCALE, sc.w * ATT_SCALE);
      const int sgo = wbase + (st << 4) + sq;  // chunk-local s
      if (sgo < n) m4 = f4max(m4, scores);
      if (dg == 0) *reinterpret_cast<float4*>(&pt[wbase + (st << 4) + sq][0]) = scores;
    }
  }

  // ---- block softmax ----
#pragma unroll
  for (int off = 4; off <= 32; off <<= 1) {
    m4.x = fmaxf(m4.x, __shfl_xor(m4.x, off));
    m4.y = fmaxf(m4.y, __shfl_xor(m4.y, off));
    m4.z = fmaxf(m4.z, __shfl_xor(m4.z, off));
    m4.w = fmaxf(m4.w, __shfl_xor(m4.w, off));
  }
  if (l == 0) *reinterpret_cast<float4*>(&redm[w][0]) = m4;
  __syncthreads();
  float4 M4 = *reinterpret_cast<const float4*>(&redm[0][0]);
  M4 = f4max(M4, *reinterpret_cast<const float4*>(&redm[1][0]));
  M4 = f4max(M4, *reinterpret_cast<const float4*>(&redm[2][0]));
  M4 = f4max(M4, *reinterpret_cast<const float4*>(&redm[3][0]));

  float4 l4 = make_float4(0.f, 0.f, 0.f, 0.f);
#pragma unroll
  for (int i = 0; i < 2; ++i) {
    const int s = t + (i << 8);
    float4 e = make_float4(0.f, 0.f, 0.f, 0.f);
    if (s < n) {
      const float4 v = *reinterpret_cast<const float4*>(&pt[s][0]);
      e.x = __expf(v.x - M4.x);
      e.y = __expf(v.y - M4.y);
      e.z = __expf(v.z - M4.z);
      e.w = __expf(v.w - M4.w);
      l4.x += e.x; l4.y += e.y; l4.z += e.z; l4.w += e.w;
    }
    *reinterpret_cast<float4*>(&pt[s][0]) = e;  // zeros beyond n
  }
#pragma unroll
  for (int off = 1; off <= 32; off <<= 1) {
    l4.x += __shfl_xor(l4.x, off);
    l4.y += __shfl_xor(l4.y, off);
    l4.z += __shfl_xor(l4.z, off);
    l4.w += __shfl_xor(l4.w, off);
  }
  if (l == 0) *reinterpret_cast<float4*>(&redl[w][0]) = l4;
  __syncthreads();
  if (t == 0) {
    float4 Ltot = *reinterpret_cast<const float4*>(&redl[0][0]);
    const float4 l1 = *reinterpret_cast<const float4*>(&redl[1][0]);
    const float4 l2 = *reinterpret_cast<const float4*>(&redl[2][0]);
    const float4 l3 = *reinterpret_cast<const float4*>(&redl[3][0]);
    Ltot.x += l1.x + l2.x + l3.x;
    Ltot.y += l1.y + l2.y + l3.y;
    Ltot.z += l1.z + l2.z + l3.z;
    Ltot.w += l1.w + l2.w + l3.w;
    *reinterpret_cast<float4*>(ml + (size_t)bid * 8) = M4;
    *reinterpret_cast<float4*>(ml + (size_t)bid * 8 + 4) = Ltot;
  }

  // ---- PV phase ----
  const int d = t & 127, shalf = t >> 7;
  float4 acc = make_float4(0.f, 0.f, 0.f, 0.f);
  const int ntiles = (n + 63) >> 6;
  for (int vt = 0; vt < ntiles; ++vt) {
    const int base = start + (vt << 6);
    __syncthreads();  // protect tile from previous readers
#pragma unroll
    for (int i = 0; i < 8; ++i) {
      const int idx = t + (i << 8);
      const int sl = idx >> 5, d4 = idx & 31;
      const int sg = base + sl;
      const float4 v =
          (sg == slot)
              ? *reinterpret_cast<const float4*>(vnew + (d4 << 2))
              : *reinterpret_cast<const float4*>(cache + ((size_t)((b << 12) + sg) << 10) + 512 +
                                                 (kvh << 7) + (d4 << 2));
      *reinterpret_cast<float4*>(&tile[sl][d4 << 2]) = v;
    }
    __syncthreads();
    const int pbase = vt << 6;
#pragma unroll
    for (int i = 0; i < 32; ++i) {
      const int sl = (shalf << 5) + i;
      const float4 p4 = *reinterpret_cast<const float4*>(&pt[pbase + sl][0]);
      const float vv = tile[sl][d];
      acc.x = fmaf(p4.x, vv, acc.x);
      acc.y = fmaf(p4.y, vv, acc.y);
      acc.z = fmaf(p4.z, vv, acc.z);
      acc.w = fmaf(p4.w, vv, acc.w);
    }
  }
  __syncthreads();
  if (shalf == 1) *reinterpret_cast<float4*>(&obuf[d][0]) = acc;
  __syncthreads();
  if (shalf == 0) {
    const float4 o2 = *reinterpret_cast<const float4*>(&obuf[d][0]);
    acc.x += o2.x; acc.y += o2.y; acc.z += o2.z; acc.w += o2.w;
    float* ap = accp + (size_t)bid * 512;
    ap[d] = acc.x;
    ap[128 + d] = acc.y;
    ap[256 + d] = acc.z;
    ap[384 + d] = acc.w;
  }
}

// ---------------------------------------------------------------------------
// Combine chunk partials -> attn_out[32][2048]. grid 128 (b*4+kv), block 128.
// ---------------------------------------------------------------------------
__global__ __launch_bounds__(128) void combine_kernel(const int* __restrict__ seq_lens,
                                                      const float* __restrict__ ml,
                                                      const float* __restrict__ accp,
                                                      float* __restrict__ attn) {
  const int blk = blockIdx.x;
  const int b = blk >> 2, kvh = blk & 3;
  const int d = threadIdx.x;
  const int L = seq_lens[b];
  const int nch = (L + 511) >> 9;
  const int base = b * 32 + kvh * 8;

  float4 M4 = make_float4(-1e30f, -1e30f, -1e30f, -1e30f);
  for (int c = 0; c < nch; ++c) {
    const float4 mc = *reinterpret_cast<const float4*>(ml + (size_t)(base + c) * 8);
    M4 = f4max(M4, mc);
  }
  float4 osum = make_float4(0.f, 0.f, 0.f, 0.f);
  float4 lsum = make_float4(0.f, 0.f, 0.f, 0.f);
  for (int c = 0; c < nch; ++c) {
    const int idx = base + c;
    const float4 mc = *reinterpret_cast<const float4*>(ml + (size_t)idx * 8);
    const float4 lc = *reinterpret_cast<const float4*>(ml + (size_t)idx * 8 + 4);
    float4 wg;
    wg.x = __expf(mc.x - M4.x);
    wg.y = __expf(mc.y - M4.y);
    wg.z = __expf(mc.z - M4.z);
    wg.w = __expf(mc.w - M4.w);
    lsum.x = fmaf(lc.x, wg.x, lsum.x);
    lsum.y = fmaf(lc.y, wg.y, lsum.y);
    lsum.z = fmaf(lc.z, wg.z, lsum.z);
    lsum.w = fmaf(lc.w, wg.w, lsum.w);
    const float* ap = accp + (size_t)idx * 512;
    osum.x = fmaf(wg.x, ap[d], osum.x);
    osum.y = fmaf(wg.y, ap[128 + d], osum.y);
    osum.z = fmaf(wg.z, ap[256 + d], osum.z);
    osum.w = fmaf(wg.w, ap[384 + d], osum.w);
  }
  float* op = attn + (size_t)b * HQ + kvh * 512;
  op[d] = osum.x / lsum.x;
  op[128 + d] = osum.y / lsum.y;
  op[256 + d] = osum.z / lsum.z;
  op[384 + d] = osum.w / lsum.w;
}

// ---------------------------------------------------------------------------
extern "C" void kernel_launch(void* const* d_in, const int* in_sizes, int n_in,
                              void* d_out, int out_size, void* d_ws, size_t ws_size,
                              hipStream_t stream) {
  const float* hidden = (const float*)d_in[0];
  // d_in[1] positions: unused by the reference computation
  const float* cache = (const float*)d_in[2];
  const int* slot_map = (const int*)d_in[3];
  const int* seq_lens = (const int*)d_in[4];
  const float* Wqkv = (const float*)d_in[5];
  const float* bqkv = (const float*)d_in[6];
  const float* Wo = (const float*)d_in[7];
  float* out = (float*)d_out;
  float* ws = (float*)d_ws;

  float* qkv_part = ws;                   // 8*32*3072 = 786432
  float* qkv      = ws + 786432;          // 32*3072   =  98304
  float* ml       = ws + 884736;          // 1024*8    =   8192
  float* accp     = ws + 892928;          // 1024*512  = 524288
  float* attn     = ws + 1417216;         // 32*2048   =  65536
  float* o_part   = ws + 1482752;         // 8*32*2048 = 524288

  proj_kernel<QKV_N><<<dim3(48, 8), 256, 0, stream>>>(hidden, Wqkv, qkv_part);
  reduce_kernel<QKV_N, true><<<384, 256, 0, stream>>>(qkv_part, bqkv, qkv);
  attn_kernel<<<1024, 256, 0, stream>>>(cache, seq_lens, slot_map, qkv, ml, accp);
  combine_kernel<<<128, 128, 0, stream>>>(seq_lens, ml, accp, attn);
  proj_kernel<HQ><<<dim3(32, 8), 256, 0, stream>>>(attn, Wo, o_part);
  reduce_kernel<HQ, false><<<256, 256, 0, stream>>>(o_part, nullptr, out);
}

// Round 2
// 180.477 us; speedup vs baseline: 1.0950x; 1.0950x over previous
//
#include <hip/hip_runtime.h>
#include <cstddef>

#define HQ 2048
#define NKVH 4
#define HDIM 128
#define QKV_N 3072
#define ATT_SCALE 0.08838834764831845f
#define KSPLIT 16
#define CHUNK 256
#define NCH 16

__device__ __forceinline__ float4 f4max(float4 a, float4 b) {
  return make_float4(fmaxf(a.x, b.x), fmaxf(a.y, b.y), fmaxf(a.z, b.z), fmaxf(a.w, b.w));
}

// ---------------------------------------------------------------------------
// Projection: part[ksb][32][N] = X[32][2048] @ W[k-slice][N], K-split 16x128.
// grid (N/64, 16), block 256 = 64 cols x 4 ksub (32 K each).
// ---------------------------------------------------------------------------
template <int N>
__global__ __launch_bounds__(256) void proj_kernel(const float* __restrict__ X,
                                                   const float* __restrict__ W,
                                                   float* __restrict__ part) {
  __shared__ union {
    float x[32][128];
    float red[32][4][64];
  } sm;
  const int t = threadIdx.x;
  const int c0 = blockIdx.x << 6;
  const int ksb = blockIdx.y;
  const int k0 = ksb << 7;
  const int c = t & 63;
  const int ksub = t >> 6;

  // stage X slab [32][128] once
#pragma unroll
  for (int i = 0; i < 4; ++i) {
    const int id = t + (i << 8);
    const int bb = id >> 5, kk = (id & 31) << 2;
    *reinterpret_cast<float4*>(&sm.x[bb][kk]) =
        *reinterpret_cast<const float4*>(X + bb * HQ + k0 + kk);
  }
  __syncthreads();

  float acc[32];
#pragma unroll
  for (int b = 0; b < 32; ++b) acc[b] = 0.f;

#pragma unroll
  for (int kk4 = 0; kk4 < 8; ++kk4) {
    const int kk = (ksub << 5) + (kk4 << 2);
    const float* wp = W + (size_t)(k0 + kk) * N + c0 + c;
    const float w0 = wp[0];
    const float w1 = wp[N];
    const float w2 = wp[2 * N];
    const float w3 = wp[3 * N];
#pragma unroll
    for (int b = 0; b < 32; ++b) {
      const float4 x4 = *reinterpret_cast<const float4*>(&sm.x[b][kk]);
      acc[b] = fmaf(x4.x, w0, acc[b]);
      acc[b] = fmaf(x4.y, w1, acc[b]);
      acc[b] = fmaf(x4.z, w2, acc[b]);
      acc[b] = fmaf(x4.w, w3, acc[b]);
    }
  }
  __syncthreads();  // x slab dead; union reuse as red
#pragma unroll
  for (int b = 0; b < 32; ++b) sm.red[b][ksub][c] = acc[b];
  __syncthreads();
#pragma unroll
  for (int i = 0; i < 8; ++i) {
    const int o = t + (i << 8);
    const int b = o >> 6, cc = o & 63;
    const float v = sm.red[b][0][cc] + sm.red[b][1][cc] + sm.red[b][2][cc] + sm.red[b][3][cc];
    part[(size_t)(ksb * 32 + b) * N + c0 + cc] = v;
  }
}

// ---------------------------------------------------------------------------
// Reduce K-split partials (+ optional bias)
// ---------------------------------------------------------------------------
template <int NCOL, bool HAS_BIAS>
__global__ __launch_bounds__(256) void reduce_kernel(const float* __restrict__ part,
                                                     const float* __restrict__ bias,
                                                     float* __restrict__ out) {
  const int o = blockIdx.x * 256 + threadIdx.x;
  constexpr int total = 32 * NCOL;
  float s = 0.f;
#pragma unroll
  for (int ks = 0; ks < KSPLIT; ++ks) s += part[(size_t)ks * total + o];
  if (HAS_BIAS) s += bias[o % NCOL];
  out[o] = s;
}

// ---------------------------------------------------------------------------
// Flash-decode attention, CHUNK=256, wave-private rows. grid 32*4*16=2048.
// Each wave owns 64 rows (4 subtiles of 16) for both QK^T and PV.
// ---------------------------------------------------------------------------
__global__ __launch_bounds__(256) void attn_kernel(const float* __restrict__ cache,
                                                   const int* __restrict__ seq_lens,
                                                   const int* __restrict__ slot_map,
                                                   const float* __restrict__ qkv,
                                                   float* __restrict__ ml,
                                                   float* __restrict__ accp) {
  __shared__ float tile[4][16][132];  // per-wave K subtile, chunk-33 layout
  __shared__ union {
    float qt[4][516];       // 4 bank-shifted copies of q^T [d*4+g]
    float pv[4][128][4];    // per-wave PV partials (after barrier #1)
  } u;
  __shared__ float pt[CHUNK][4];
  __shared__ float redm[4][4];
  __shared__ float redl[4][4];

  const int t = threadIdx.x;
  const int bid = blockIdx.x;
  const int chunk = bid & 15;
  const int kvh = (bid >> 4) & 3;
  const int b = bid >> 6;
  const int L = seq_lens[b];
  const int start = chunk << 8;
  if (start >= L) return;
  const int n = min(CHUNK, L - start);
  const int send = start + n;
  const int slot = slot_map[b];
  const float* __restrict__ qrow = qkv + b * QKV_N;
  const float* __restrict__ knew = qrow + 2048 + (kvh << 7);
  const float* __restrict__ vnew = qrow + 2560 + (kvh << 7);

  const int w = t >> 6, l = t & 63;
  const int sq = l >> 2, dg = l & 3;
  const int wbase = w << 6;
  float* tw = &tile[w][0][0];

  // fill qt: qt[cp][d*4+g] = q[kvh*4+g][d]
#pragma unroll
  for (int i = 0; i < 8; ++i) {
    const int idx = t + (i << 8);
    const int cp = idx >> 9, rem = idx & 511;
    u.qt[cp][rem] = qrow[((kvh << 2) + (rem & 3)) * HDIM + (rem >> 2)];
  }
  __syncthreads();  // barrier #0

  float4 ra[8];
  float2 va[16], vb[16];

  auto kload = [&](int st, float4* r) {
    const int sb = start + wbase + (st << 4);
#pragma unroll
    for (int i = 0; i < 8; ++i) {
      const int idx = l + (i << 6);
      const int sl = idx >> 5, d4 = idx & 31;
      int sg = sb + sl;
      sg = (sg < send) ? sg : start;  // clamp: garbage rows masked later
      const float* p = (sg == slot)
                           ? (knew + (d4 << 2))
                           : (cache + (((size_t)((b << 12) + sg)) << 10) + (kvh << 7) + (d4 << 2));
      r[i] = *reinterpret_cast<const float4*>(p);
    }
  };
  auto vload = [&](int st, float2* rv) {
    const int sb = start + wbase + (st << 4);
#pragma unroll
    for (int s = 0; s < 16; ++s) {
      int sg = sb + s;
      sg = (sg < send) ? sg : start;
      const float* p = (sg == slot)
                           ? vnew
                           : (cache + (((size_t)((b << 12) + sg)) << 10) + 512 + (kvh << 7));
      rv[s] = *reinterpret_cast<const float2*>(p + (l << 1));
    }
  };

  kload(0, ra);
  vload(0, va);  // in flight during entire K phase

  float4 m4 = make_float4(-1e30f, -1e30f, -1e30f, -1e30f);
#pragma unroll
  for (int st = 0; st < 4; ++st) {
    // stage ra -> LDS (chunk-33: row = sl*132, dim-chunk c at 33c)
#pragma unroll
    for (int i = 0; i < 8; ++i) {
      const int idx = l + (i << 6);
      const int sl = idx >> 5, d4 = idx & 31;
      *reinterpret_cast<float4*>(tw + sl * 132 + 33 * (d4 >> 3) + ((d4 & 7) << 2)) = ra[i];
    }
    if (st < 3) kload(st + 1, ra);  // WAR on regs: ds_write reads precede reload
    asm volatile("s_waitcnt lgkmcnt(0)" ::: "memory");
    const float* trow = tw + sq * 132 + 33 * dg;
    const float* qtp = &u.qt[dg][0];
    float4 sc = make_float4(0.f, 0.f, 0.f, 0.f);
#pragma unroll
    for (int i = 0; i < 8; ++i) {
      const float4 k4 = *reinterpret_cast<const float4*>(trow + (i << 2));
      const float* qb = qtp + (((dg << 3) + i) << 4);
      const float4 q0 = *reinterpret_cast<const float4*>(qb);
      const float4 q1 = *reinterpret_cast<const float4*>(qb + 4);
      const float4 q2 = *reinterpret_cast<const float4*>(qb + 8);
      const float4 q3 = *reinterpret_cast<const float4*>(qb + 12);
      sc.x = fmaf(k4.x, q0.x, sc.x); sc.y = fmaf(k4.x, q0.y, sc.y);
      sc.z = fmaf(k4.x, q0.z, sc.z); sc.w = fmaf(k4.x, q0.w, sc.w);
      sc.x = fmaf(k4.y, q1.x, sc.x); sc.y = fmaf(k4.y, q1.y, sc.y);
      sc.z = fmaf(k4.y, q1.z, sc.z); sc.w = fmaf(k4.y, q1.w, sc.w);
      sc.x = fmaf(k4.z, q2.x, sc.x); sc.y = fmaf(k4.z, q2.y, sc.y);
      sc.z = fmaf(k4.z, q2.z, sc.z); sc.w = fmaf(k4.z, q2.w, sc.w);
      sc.x = fmaf(k4.w, q3.x, sc.x); sc.y = fmaf(k4.w, q3.y, sc.y);
      sc.z = fmaf(k4.w, q3.z, sc.z); sc.w = fmaf(k4.w, q3.w, sc.w);
    }
    // sum over the 4 dim-groups (adjacent lanes)
    sc.x += __shfl_xor(sc.x, 1); sc.y += __shfl_xor(sc.y, 1);
    sc.z += __shfl_xor(sc.z, 1); sc.w += __shfl_xor(sc.w, 1);
    sc.x += __shfl_xor(sc.x, 2); sc.y += __shfl_xor(sc.y, 2);
    sc.z += __shfl_xor(sc.z, 2); sc.w += __shfl_xor(sc.w, 2);
    const float4 scores = make_float4(sc.x * ATT_SCALE, sc.y * ATT_SCALE,
                                      sc.z * ATT_SCALE, sc.w * ATT_SCALE);
    const int row = wbase + (st << 4) + sq;
    if (row < n) m4 = f4max(m4, scores);
    if (dg == 0) *reinterpret_cast<float4*>(&pt[row][0]) = scores;
  }

  // wave max (replicated over dg; reduce over sq)
#pragma unroll
  for (int off = 4; off <= 32; off <<= 1) {
    m4.x = fmaxf(m4.x, __shfl_xor(m4.x, off));
    m4.y = fmaxf(m4.y, __shfl_xor(m4.y, off));
    m4.z = fmaxf(m4.z, __shfl_xor(m4.z, off));
    m4.w = fmaxf(m4.w, __shfl_xor(m4.w, off));
  }
  if (l == 0) *reinterpret_cast<float4*>(&redm[w][0]) = m4;
  __syncthreads();  // barrier #1 (also separates qt reads from pv writes)
  float4 M4 = *reinterpret_cast<const float4*>(&redm[0][0]);
  M4 = f4max(M4, *reinterpret_cast<const float4*>(&redm[1][0]));
  M4 = f4max(M4, *reinterpret_cast<const float4*>(&redm[2][0]));
  M4 = f4max(M4, *reinterpret_cast<const float4*>(&redm[3][0]));

  // exp own rows (wave-private), accumulate l
  {
    const int r = wbase + l;
    float4 e = make_float4(0.f, 0.f, 0.f, 0.f);
    if (r < n) {
      const float4 v = *reinterpret_cast<const float4*>(&pt[r][0]);
      e.x = __expf(v.x - M4.x);
      e.y = __expf(v.y - M4.y);
      e.z = __expf(v.z - M4.z);
      e.w = __expf(v.w - M4.w);
    }
    *reinterpret_cast<float4*>(&pt[r][0]) = e;
    float4 l4 = e;
#pragma unroll
    for (int off = 1; off <= 32; off <<= 1) {
      l4.x += __shfl_xor(l4.x, off);
      l4.y += __shfl_xor(l4.y, off);
      l4.z += __shfl_xor(l4.z, off);
      l4.w += __shfl_xor(l4.w, off);
    }
    if (l == 0) *reinterpret_cast<float4*>(&redl[w][0]) = l4;
  }

  // PV (wave-private): lane l covers dims 2l, 2l+1 for 4 heads
  float4 accA = make_float4(0.f, 0.f, 0.f, 0.f);
  float4 accB = make_float4(0.f, 0.f, 0.f, 0.f);
#pragma unroll
  for (int vt = 0; vt < 4; ++vt) {
    float2* cur = (vt & 1) ? vb : va;
    float2* nxt = (vt & 1) ? va : vb;
    if (vt < 3) vload(vt + 1, nxt);
#pragma unroll
    for (int s = 0; s < 16; ++s) {
      const float4 p = *reinterpret_cast<const float4*>(&pt[wbase + (vt << 4) + s][0]);
      const float2 vv = cur[s];
      accA.x = fmaf(p.x, vv.x, accA.x); accA.y = fmaf(p.y, vv.x, accA.y);
      accA.z = fmaf(p.z, vv.x, accA.z); accA.w = fmaf(p.w, vv.x, accA.w);
      accB.x = fmaf(p.x, vv.y, accB.x); accB.y = fmaf(p.y, vv.y, accB.y);
      accB.z = fmaf(p.z, vv.y, accB.z); accB.w = fmaf(p.w, vv.y, accB.w);
    }
  }

  *reinterpret_cast<float4*>(&u.pv[w][l << 1][0]) = accA;
  *reinterpret_cast<float4*>(&u.pv[w][(l << 1) + 1][0]) = accB;
  __syncthreads();  // barrier #2

  if (t < 128) {
    const int d = t;
    float4 s0 = *reinterpret_cast<const float4*>(&u.pv[0][d][0]);
    const float4 s1 = *reinterpret_cast<const float4*>(&u.pv[1][d][0]);
    const float4 s2 = *reinterpret_cast<const float4*>(&u.pv[2][d][0]);
    const float4 s3 = *reinterpret_cast<const float4*>(&u.pv[3][d][0]);
    s0.x += s1.x + s2.x + s3.x;
    s0.y += s1.y + s2.y + s3.y;
    s0.z += s1.z + s2.z + s3.z;
    s0.w += s1.w + s2.w + s3.w;
    float* ap = accp + (size_t)bid * 512;
    ap[d] = s0.x;
    ap[128 + d] = s0.y;
    ap[256 + d] = s0.z;
    ap[384 + d] = s0.w;
  }
  if (t == 0) {
    float4 Lt = *reinterpret_cast<const float4*>(&redl[0][0]);
    const float4 l1 = *reinterpret_cast<const float4*>(&redl[1][0]);
    const float4 l2 = *reinterpret_cast<const float4*>(&redl[2][0]);
    const float4 l3 = *reinterpret_cast<const float4*>(&redl[3][0]);
    Lt.x += l1.x + l2.x + l3.x;
    Lt.y += l1.y + l2.y + l3.y;
    Lt.z += l1.z + l2.z + l3.z;
    Lt.w += l1.w + l2.w + l3.w;
    *reinterpret_cast<float4*>(ml + (size_t)bid * 8) = M4;
    *reinterpret_cast<float4*>(ml + (size_t)bid * 8 + 4) = Lt;
  }
}

// ---------------------------------------------------------------------------
// Combine chunk partials. grid 512 = (b,kvh,g), block 128 (d).
// ---------------------------------------------------------------------------
__global__ __launch_bounds__(128) void combine_kernel(const int* __restrict__ seq_lens,
                                                      const float* __restrict__ ml,
                                                      const float* __restrict__ accp,
                                                      float* __restrict__ attn) {
  const int blk = blockIdx.x;
  const int g = blk & 3, kvh = (blk >> 2) & 3, b = blk >> 4;
  const int d = threadIdx.x;
  const int L = seq_lens[b];
  const int nch = (L + CHUNK - 1) >> 8;
  const int base = (b * 4 + kvh) * NCH;

  float M = -1e30f;
  for (int c = 0; c < nch; ++c) M = fmaxf(M, ml[(size_t)(base + c) * 8 + g]);
  float osum = 0.f, lsum = 0.f;
  for (int c = 0; c < nch; ++c) {
    const int idx = base + c;
    const float mc = ml[(size_t)idx * 8 + g];
    const float lc = ml[(size_t)idx * 8 + 4 + g];
    const float wgt = __expf(mc - M);
    lsum = fmaf(lc, wgt, lsum);
    osum = fmaf(wgt, accp[(size_t)idx * 512 + g * 128 + d], osum);
  }
  attn[(size_t)b * HQ + kvh * 512 + g * 128 + d] = osum / lsum;
}

// ---------------------------------------------------------------------------
extern "C" void kernel_launch(void* const* d_in, const int* in_sizes, int n_in,
                              void* d_out, int out_size, void* d_ws, size_t ws_size,
                              hipStream_t stream) {
  const float* hidden = (const float*)d_in[0];
  const float* cache = (const float*)d_in[2];
  const int* slot_map = (const int*)d_in[3];
  const int* seq_lens = (const int*)d_in[4];
  const float* Wqkv = (const float*)d_in[5];
  const float* bqkv = (const float*)d_in[6];
  const float* Wo = (const float*)d_in[7];
  float* out = (float*)d_out;
  float* ws = (float*)d_ws;

  float* qkv_part = ws;            // 16*32*3072 = 1,572,864
  float* qkv      = ws + 1572864;  // 98,304
  float* ml       = ws + 1671168;  // 2048*8 = 16,384
  float* accp     = ws + 1687552;  // 2048*512 = 1,048,576
  float* attn     = ws + 2736128;  // 65,536
  float* o_part   = ws + 2801664;  // 16*32*2048 = 1,048,576

  proj_kernel<QKV_N><<<dim3(48, KSPLIT), 256, 0, stream>>>(hidden, Wqkv, qkv_part);
  reduce_kernel<QKV_N, true><<<384, 256, 0, stream>>>(qkv_part, bqkv, qkv);
  attn_kernel<<<2048, 256, 0, stream>>>(cache, seq_lens, slot_map, qkv, ml, accp);
  combine_kernel<<<512, 128, 0, stream>>>(seq_lens, ml, accp, attn);
  proj_kernel<HQ><<<dim3(32, KSPLIT), 256, 0, stream>>>(attn, Wo, o_part);
  reduce_kernel<HQ, false><<<256, 256, 0, stream>>>(o_part, nullptr, out);
}

// Round 3
// 124.999 us; speedup vs baseline: 1.5810x; 1.4438x over previous
//
#include <hip/hip_runtime.h>
#include <cstddef>

#define HQ 2048
#define NKVH 4
#define HDIM 128
#define QKV_N 3072
#define ATT_SCALE 0.08838834764831845f
#define KSPLIT 16
#define CHUNK 128
#define NCH 32

__device__ __forceinline__ float4 f4max(float4 a, float4 b) {
  return make_float4(fmaxf(a.x, b.x), fmaxf(a.y, b.y), fmaxf(a.z, b.z), fmaxf(a.w, b.w));
}

// ---------------------------------------------------------------------------
// Projection: part[ksb][32][N] = X[32][2048] @ W[k-slice][N], K-split 16x128.
// grid (N/64, 16), block 256 = 64 cols x 4 ksub (32 K each).
// ---------------------------------------------------------------------------
template <int N>
__global__ __launch_bounds__(256) void proj_kernel(const float* __restrict__ X,
                                                   const float* __restrict__ W,
                                                   float* __restrict__ part) {
  __shared__ union {
    float x[32][128];
    float red[32][4][64];
  } sm;
  const int t = threadIdx.x;
  const int c0 = blockIdx.x << 6;
  const int ksb = blockIdx.y;
  const int k0 = ksb << 7;
  const int c = t & 63;
  const int ksub = t >> 6;

#pragma unroll
  for (int i = 0; i < 4; ++i) {
    const int id = t + (i << 8);
    const int bb = id >> 5, kk = (id & 31) << 2;
    *reinterpret_cast<float4*>(&sm.x[bb][kk]) =
        *reinterpret_cast<const float4*>(X + bb * HQ + k0 + kk);
  }
  __syncthreads();

  float acc[32];
#pragma unroll
  for (int b = 0; b < 32; ++b) acc[b] = 0.f;

#pragma unroll
  for (int kk4 = 0; kk4 < 8; ++kk4) {
    const int kk = (ksub << 5) + (kk4 << 2);
    const float* wp = W + (size_t)(k0 + kk) * N + c0 + c;
    const float w0 = wp[0];
    const float w1 = wp[N];
    const float w2 = wp[2 * N];
    const float w3 = wp[3 * N];
#pragma unroll
    for (int b = 0; b < 32; ++b) {
      const float4 x4 = *reinterpret_cast<const float4*>(&sm.x[b][kk]);
      acc[b] = fmaf(x4.x, w0, acc[b]);
      acc[b] = fmaf(x4.y, w1, acc[b]);
      acc[b] = fmaf(x4.z, w2, acc[b]);
      acc[b] = fmaf(x4.w, w3, acc[b]);
    }
  }
  __syncthreads();
#pragma unroll
  for (int b = 0; b < 32; ++b) sm.red[b][ksub][c] = acc[b];
  __syncthreads();
#pragma unroll
  for (int i = 0; i < 8; ++i) {
    const int o = t + (i << 8);
    const int b = o >> 6, cc = o & 63;
    const float v = sm.red[b][0][cc] + sm.red[b][1][cc] + sm.red[b][2][cc] + sm.red[b][3][cc];
    part[(size_t)(ksb * 32 + b) * N + c0 + cc] = v;
  }
}

template <int NCOL, bool HAS_BIAS>
__global__ __launch_bounds__(256) void reduce_kernel(const float* __restrict__ part,
                                                     const float* __restrict__ bias,
                                                     float* __restrict__ out) {
  const int o = blockIdx.x * 256 + threadIdx.x;
  constexpr int total = 32 * NCOL;
  float s = 0.f;
#pragma unroll
  for (int ks = 0; ks < KSPLIT; ++ks) s += part[(size_t)ks * total + o];
  if (HAS_BIAS) s += bias[o % NCOL];
  out[o] = s;
}

// ---------------------------------------------------------------------------
// Flash-decode attention, CHUNK=128, all K/V global->register (no staging).
// grid 32*4*32 = 4096, block 256. Wave owns 32 rows: score via 16-lane dot
// (q in 32 regs/lane), PV via float2/lane with ping-pong prefetch.
// ---------------------------------------------------------------------------
__global__ __launch_bounds__(256) void attn_kernel(const float* __restrict__ cache,
                                                   const int* __restrict__ seq_lens,
                                                   const int* __restrict__ slot_map,
                                                   const float* __restrict__ qkv,
                                                   float* __restrict__ ml,
                                                   float* __restrict__ accp) {
  __shared__ float pt[CHUNK][4];
  __shared__ float pvbuf[4][128][4];
  __shared__ float redm[4][4];
  __shared__ float redl[4][4];

  const int t = threadIdx.x;
  const int bid = blockIdx.x;
  const int chunk = bid & 31;
  const int kvh = (bid >> 5) & 3;
  const int b = bid >> 7;
  const int L = seq_lens[b];
  const int start = chunk << 7;
  if (start >= L) return;
  const int n = min(CHUNK, L - start);
  const int send = start + n;
  const int slot = slot_map[b];
  const float* __restrict__ qrow = qkv + b * QKV_N;
  const float* __restrict__ knew = qrow + 2048 + (kvh << 7);
  const float* __restrict__ vnew = qrow + 2560 + (kvh << 7);

  const int w = t >> 6, l = t & 63;
  const int l16 = l & 15, rq = l >> 4;
  const int wbase = w << 5;  // 32 rows per wave

  // q in regs: qr[g][e] = q[kvh*4+g][l16*8 + e*4 ..]
  float4 qr[4][2];
#pragma unroll
  for (int g = 0; g < 4; ++g) {
#pragma unroll
    for (int e = 0; e < 2; ++e)
      qr[g][e] = *reinterpret_cast<const float4*>(qrow + ((kvh << 2) + g) * HDIM +
                                                  (l16 << 3) + (e << 2));
  }

  auto krow_ptr = [&](int r) -> const float* {
    int sg = start + r;
    sg = (sg < send) ? sg : start;  // clamp; garbage rows masked later
    return (sg == slot) ? knew : cache + (((size_t)((b << 12) + sg)) << 10) + (kvh << 7);
  };
  auto vrow_ptr = [&](int r) -> const float* {
    int sg = start + r;
    sg = (sg < send) ? sg : start;
    return (sg == slot) ? vnew : cache + (((size_t)((b << 12) + sg)) << 10) + 512 + (kvh << 7);
  };

  auto kload = [&](int st, float4* dst) {
#pragma unroll
    for (int rg = 0; rg < 4; ++rg) {
      const float* kp = krow_ptr(wbase + (st << 4) + (rg << 2) + rq) + (l16 << 3);
      dst[2 * rg] = *reinterpret_cast<const float4*>(kp);
      dst[2 * rg + 1] = *reinterpret_cast<const float4*>(kp + 4);
    }
  };
  auto vload = [&](int vt, float2* dst) {
#pragma unroll
    for (int s = 0; s < 16; ++s)
      dst[s] = *reinterpret_cast<const float2*>(vrow_ptr(wbase + (vt << 4) + s) + (l << 1));
  };

  float4 m4 = make_float4(-1e30f, -1e30f, -1e30f, -1e30f);
  auto score_st = [&](int st, const float4* kr) {
#pragma unroll
    for (int rg = 0; rg < 4; ++rg) {
      const float4 k0 = kr[2 * rg], k1 = kr[2 * rg + 1];
      float s0 = fmaf(k0.x, qr[0][0].x, fmaf(k0.y, qr[0][0].y, fmaf(k0.z, qr[0][0].z, k0.w * qr[0][0].w)));
      s0 = fmaf(k1.x, qr[0][1].x, fmaf(k1.y, qr[0][1].y, fmaf(k1.z, qr[0][1].z, fmaf(k1.w, qr[0][1].w, s0))));
      float s1 = fmaf(k0.x, qr[1][0].x, fmaf(k0.y, qr[1][0].y, fmaf(k0.z, qr[1][0].z, k0.w * qr[1][0].w)));
      s1 = fmaf(k1.x, qr[1][1].x, fmaf(k1.y, qr[1][1].y, fmaf(k1.z, qr[1][1].z, fmaf(k1.w, qr[1][1].w, s1))));
      float s2 = fmaf(k0.x, qr[2][0].x, fmaf(k0.y, qr[2][0].y, fmaf(k0.z, qr[2][0].z, k0.w * qr[2][0].w)));
      s2 = fmaf(k1.x, qr[2][1].x, fmaf(k1.y, qr[2][1].y, fmaf(k1.z, qr[2][1].z, fmaf(k1.w, qr[2][1].w, s2))));
      float s3 = fmaf(k0.x, qr[3][0].x, fmaf(k0.y, qr[3][0].y, fmaf(k0.z, qr[3][0].z, k0.w * qr[3][0].w)));
      s3 = fmaf(k1.x, qr[3][1].x, fmaf(k1.y, qr[3][1].y, fmaf(k1.z, qr[3][1].z, fmaf(k1.w, qr[3][1].w, s3))));
#pragma unroll
      for (int off = 1; off <= 8; off <<= 1) {
        s0 += __shfl_xor(s0, off);
        s1 += __shfl_xor(s1, off);
        s2 += __shfl_xor(s2, off);
        s3 += __shfl_xor(s3, off);
      }
      const int row = wbase + (st << 4) + (rg << 2) + rq;
      const float4 sc = make_float4(s0 * ATT_SCALE, s1 * ATT_SCALE, s2 * ATT_SCALE, s3 * ATT_SCALE);
      if (row < n) m4 = f4max(m4, sc);
      if (l16 == 0) *reinterpret_cast<float4*>(&pt[row][0]) = sc;
    }
  };

  float4 ka[8];
  float2 va[16], vb[16];
  kload(0, ka);
  vload(0, va);  // in flight through whole score phase
  score_st(0, ka);
  kload(1, ka);
  score_st(1, ka);

  // wave max across row groups (bits 4,5 of lane)
  m4.x = fmaxf(m4.x, __shfl_xor(m4.x, 16));
  m4.y = fmaxf(m4.y, __shfl_xor(m4.y, 16));
  m4.z = fmaxf(m4.z, __shfl_xor(m4.z, 16));
  m4.w = fmaxf(m4.w, __shfl_xor(m4.w, 16));
  m4.x = fmaxf(m4.x, __shfl_xor(m4.x, 32));
  m4.y = fmaxf(m4.y, __shfl_xor(m4.y, 32));
  m4.z = fmaxf(m4.z, __shfl_xor(m4.z, 32));
  m4.w = fmaxf(m4.w, __shfl_xor(m4.w, 32));
  if (l == 0) *reinterpret_cast<float4*>(&redm[w][0]) = m4;
  __syncthreads();  // barrier A
  float4 M4 = *reinterpret_cast<const float4*>(&redm[0][0]);
  M4 = f4max(M4, *reinterpret_cast<const float4*>(&redm[1][0]));
  M4 = f4max(M4, *reinterpret_cast<const float4*>(&redm[2][0]));
  M4 = f4max(M4, *reinterpret_cast<const float4*>(&redm[3][0]));

  vload(1, vb);  // hide under softmax

  float4 l4 = make_float4(0.f, 0.f, 0.f, 0.f);
  if (l < 32) {
    const int r = wbase + l;
    float4 e = make_float4(0.f, 0.f, 0.f, 0.f);
    if (r < n) {
      const float4 v = *reinterpret_cast<const float4*>(&pt[r][0]);
      e.x = __expf(v.x - M4.x);
      e.y = __expf(v.y - M4.y);
      e.z = __expf(v.z - M4.z);
      e.w = __expf(v.w - M4.w);
    }
    *reinterpret_cast<float4*>(&pt[r][0]) = e;  // zeros beyond n
    l4 = e;
  }
#pragma unroll
  for (int off = 1; off <= 32; off <<= 1) {
    l4.x += __shfl_xor(l4.x, off);
    l4.y += __shfl_xor(l4.y, off);
    l4.z += __shfl_xor(l4.z, off);
    l4.w += __shfl_xor(l4.w, off);
  }
  if (l == 0) *reinterpret_cast<float4*>(&redl[w][0]) = l4;

  // PV: lane covers dims 2l, 2l+1 for 4 heads
  float4 accA = make_float4(0.f, 0.f, 0.f, 0.f);
  float4 accB = make_float4(0.f, 0.f, 0.f, 0.f);
#pragma unroll
  for (int s = 0; s < 16; ++s) {
    const float4 p = *reinterpret_cast<const float4*>(&pt[wbase + s][0]);
    const float2 vv = va[s];
    accA.x = fmaf(p.x, vv.x, accA.x); accA.y = fmaf(p.y, vv.x, accA.y);
    accA.z = fmaf(p.z, vv.x, accA.z); accA.w = fmaf(p.w, vv.x, accA.w);
    accB.x = fmaf(p.x, vv.y, accB.x); accB.y = fmaf(p.y, vv.y, accB.y);
    accB.z = fmaf(p.z, vv.y, accB.z); accB.w = fmaf(p.w, vv.y, accB.w);
  }
#pragma unroll
  for (int s = 0; s < 16; ++s) {
    const float4 p = *reinterpret_cast<const float4*>(&pt[wbase + 16 + s][0]);
    const float2 vv = vb[s];
    accA.x = fmaf(p.x, vv.x, accA.x); accA.y = fmaf(p.y, vv.x, accA.y);
    accA.z = fmaf(p.z, vv.x, accA.z); accA.w = fmaf(p.w, vv.x, accA.w);
    accB.x = fmaf(p.x, vv.y, accB.x); accB.y = fmaf(p.y, vv.y, accB.y);
    accB.z = fmaf(p.z, vv.y, accB.z); accB.w = fmaf(p.w, vv.y, accB.w);
  }

  *reinterpret_cast<float4*>(&pvbuf[w][l << 1][0]) = accA;
  *reinterpret_cast<float4*>(&pvbuf[w][(l << 1) + 1][0]) = accB;
  __syncthreads();  // barrier B

  if (t < 128) {
    const int d = t;
    float4 s0 = *reinterpret_cast<const float4*>(&pvbuf[0][d][0]);
    const float4 s1 = *reinterpret_cast<const float4*>(&pvbuf[1][d][0]);
    const float4 s2 = *reinterpret_cast<const float4*>(&pvbuf[2][d][0]);
    const float4 s3 = *reinterpret_cast<const float4*>(&pvbuf[3][d][0]);
    s0.x += s1.x + s2.x + s3.x;
    s0.y += s1.y + s2.y + s3.y;
    s0.z += s1.z + s2.z + s3.z;
    s0.w += s1.w + s2.w + s3.w;
    float* ap = accp + (size_t)bid * 512;
    ap[d] = s0.x;
    ap[128 + d] = s0.y;
    ap[256 + d] = s0.z;
    ap[384 + d] = s0.w;
  }
  if (t == 0) {
    float4 Lt = *reinterpret_cast<const float4*>(&redl[0][0]);
    const float4 l1 = *reinterpret_cast<const float4*>(&redl[1][0]);
    const float4 l2 = *reinterpret_cast<const float4*>(&redl[2][0]);
    const float4 l3 = *reinterpret_cast<const float4*>(&redl[3][0]);
    Lt.x += l1.x + l2.x + l3.x;
    Lt.y += l1.y + l2.y + l3.y;
    Lt.z += l1.z + l2.z + l3.z;
    Lt.w += l1.w + l2.w + l3.w;
    *reinterpret_cast<float4*>(ml + (size_t)bid * 8) = M4;
    *reinterpret_cast<float4*>(ml + (size_t)bid * 8 + 4) = Lt;
  }
}

// ---------------------------------------------------------------------------
// Combine chunk partials. grid 512 = (b,kvh,g), block 128 (d).
// ---------------------------------------------------------------------------
__global__ __launch_bounds__(128) void combine_kernel(const int* __restrict__ seq_lens,
                                                      const float* __restrict__ ml,
                                                      const float* __restrict__ accp,
                                                      float* __restrict__ attn) {
  const int blk = blockIdx.x;
  const int g = blk & 3, kvh = (blk >> 2) & 3, b = blk >> 4;
  const int d = threadIdx.x;
  const int L = seq_lens[b];
  const int nch = (L + CHUNK - 1) >> 7;
  const int base = (b * 4 + kvh) * NCH;

  float M = -1e30f;
  for (int c = 0; c < nch; ++c) M = fmaxf(M, ml[(size_t)(base + c) * 8 + g]);
  float osum = 0.f, lsum = 0.f;
  for (int c = 0; c < nch; ++c) {
    const int idx = base + c;
    const float mc = ml[(size_t)idx * 8 + g];
    const float lc = ml[(size_t)idx * 8 + 4 + g];
    const float wgt = __expf(mc - M);
    lsum = fmaf(lc, wgt, lsum);
    osum = fmaf(wgt, accp[(size_t)idx * 512 + g * 128 + d], osum);
  }
  attn[(size_t)b * HQ + kvh * 512 + g * 128 + d] = osum / lsum;
}

// ---------------------------------------------------------------------------
extern "C" void kernel_launch(void* const* d_in, const int* in_sizes, int n_in,
                              void* d_out, int out_size, void* d_ws, size_t ws_size,
                              hipStream_t stream) {
  const float* hidden = (const float*)d_in[0];
  const float* cache = (const float*)d_in[2];
  const int* slot_map = (const int*)d_in[3];
  const int* seq_lens = (const int*)d_in[4];
  const float* Wqkv = (const float*)d_in[5];
  const float* bqkv = (const float*)d_in[6];
  const float* Wo = (const float*)d_in[7];
  float* out = (float*)d_out;
  float* ws = (float*)d_ws;

  float* qkv_part = ws;            // 16*32*3072 = 1,572,864
  float* qkv      = ws + 1572864;  // 98,304
  float* ml       = ws + 1671168;  // 4096*8 = 32,768
  float* accp     = ws + 1703936;  // 4096*512 = 2,097,152
  float* attn     = ws + 3801088;  // 65,536
  float* o_part   = ws + 3866624;  // 16*32*2048 = 1,048,576

  proj_kernel<QKV_N><<<dim3(48, KSPLIT), 256, 0, stream>>>(hidden, Wqkv, qkv_part);
  reduce_kernel<QKV_N, true><<<384, 256, 0, stream>>>(qkv_part, bqkv, qkv);
  attn_kernel<<<4096, 256, 0, stream>>>(cache, seq_lens, slot_map, qkv, ml, accp);
  combine_kernel<<<512, 128, 0, stream>>>(seq_lens, ml, accp, attn);
  proj_kernel<HQ><<<dim3(32, KSPLIT), 256, 0, stream>>>(attn, Wo, o_part);
  reduce_kernel<HQ, false><<<256, 256, 0, stream>>>(o_part, nullptr, out);
}